// Round 1
// baseline (257.256 us; speedup 1.0000x reference)
//
#include <hip/hip_runtime.h>

#define DPROJ 1024

// ---------------------------------------------------------------------------
// Kernel 1: classify tokens into 4 bucket lists (compaction via atomics).
// Order within a list is nondeterministic, but each token's output value is
// computed identically regardless of list position -> output deterministic.
// ---------------------------------------------------------------------------
__global__ __launch_bounds__(256) void classify_kernel(const int* __restrict__ inp, int n,
                                                       int* __restrict__ counts,
                                                       int* __restrict__ lists) {
  int t = blockIdx.x * 256 + threadIdx.x;
  if (t >= n) return;
  int v = inp[t];
  int b = (v >= 200000) ? 3 : (v >= 40000) ? 2 : (v >= 20000) ? 1 : 0;
  int pos = atomicAdd(&counts[b], 1);
  lists[b * n + pos] = t;
}

// ---------------------------------------------------------------------------
// Kernel 2: per-bucket GEMM. Tile = 64 tokens x 128 cols, K-chunks of <=64.
// 256 threads; each thread computes 4 tokens x 8 cols (cols strided by 16 to
// dodge LDS bank conflicts). fp32 VALU FMA (no fp32 MFMA on CDNA4).
// ---------------------------------------------------------------------------
template <int B, int D, int L>
__device__ __forceinline__ void gemm_body(const int* __restrict__ inp,
                                          const float* __restrict__ emb,
                                          const float* __restrict__ proj,
                                          const int* __restrict__ counts,
                                          const int* __restrict__ lists,
                                          float* __restrict__ out,
                                          int n, char* smem) {
  constexpr int TK  = (D < 64) ? D : 64;
  constexpr int LDE = TK + 4;              // pad: keeps row-stride off 32-bank period
  const int cnt = counts[B];
  const int r0  = blockIdx.y * 64;
  if (r0 >= cnt) return;
  const int c0  = blockIdx.x * 128;
  const int tid = threadIdx.x;

  float (*e_lds)[LDE] = reinterpret_cast<float (*)[LDE]>(smem);
  float (*p_lds)[LDE] = reinterpret_cast<float (*)[LDE]>(smem + 64 * LDE * 4);
  int* toks = reinterpret_cast<int*>(smem + (64 + 128) * LDE * 4);
  int* rows = toks + 64;

  if (tid < 64) {
    int p  = r0 + tid;
    int tk = (p < cnt) ? lists[B * n + p] : -1;
    toks[tid] = tk;
    rows[tid] = (tk >= 0) ? (inp[tk] - L) : 0;   // clamp pads to row 0 (valid addr)
  }
  __syncthreads();

  float acc[4][8];
#pragma unroll
  for (int i = 0; i < 4; ++i)
#pragma unroll
    for (int j = 0; j < 8; ++j) acc[i][j] = 0.f;

  const int tg = tid >> 4;   // token group 0..15 -> tokens tg*4 + {0..3}
  const int cg = tid & 15;   // col group   0..15 -> cols  c0 + cg + 16*{0..7}

  for (int k0 = 0; k0 < D; k0 += TK) {
    // stage E tile: 64 gathered rows x TK (coalesced float4 along k)
#pragma unroll
    for (int idx = tid; idx < 64 * (TK / 4); idx += 256) {
      int r  = idx / (TK / 4);
      int kk = (idx % (TK / 4)) * 4;
      float4 v = *reinterpret_cast<const float4*>(emb + (size_t)rows[r] * D + k0 + kk);
      *reinterpret_cast<float4*>(&e_lds[r][kk]) = v;
    }
    // stage P tile: 128 cols x TK
#pragma unroll
    for (int idx = tid; idx < 128 * (TK / 4); idx += 256) {
      int c  = idx / (TK / 4);
      int kk = (idx % (TK / 4)) * 4;
      float4 v = *reinterpret_cast<const float4*>(proj + (size_t)(c0 + c) * D + k0 + kk);
      *reinterpret_cast<float4*>(&p_lds[c][kk]) = v;
    }
    __syncthreads();

#pragma unroll 2
    for (int k = 0; k < TK; k += 4) {
      float4 ev[4], pv[8];
#pragma unroll
      for (int i = 0; i < 4; ++i)
        ev[i] = *reinterpret_cast<const float4*>(&e_lds[tg * 4 + i][k]);
#pragma unroll
      for (int j = 0; j < 8; ++j)
        pv[j] = *reinterpret_cast<const float4*>(&p_lds[cg + 16 * j][k]);
#pragma unroll
      for (int i = 0; i < 4; ++i)
#pragma unroll
        for (int j = 0; j < 8; ++j) {
          float a = acc[i][j];
          a = fmaf(ev[i].x, pv[j].x, a);
          a = fmaf(ev[i].y, pv[j].y, a);
          a = fmaf(ev[i].z, pv[j].z, a);
          a = fmaf(ev[i].w, pv[j].w, a);
          acc[i][j] = a;
        }
    }
    __syncthreads();
  }

  // write back: every token belongs to exactly one bucket -> plain stores,
  // no zero-init of d_out needed (all 16384 rows get fully written).
#pragma unroll
  for (int i = 0; i < 4; ++i) {
    int p = tg * 4 + i;
    if (r0 + p < cnt) {
      int tk   = toks[p];
      float* o = out + (size_t)tk * DPROJ + c0 + cg;
#pragma unroll
      for (int j = 0; j < 8; ++j) o[16 * j] = acc[i][j];
    }
  }
}

__global__ __launch_bounds__(256) void gemm_all(
    const int* __restrict__ inp,
    const float* __restrict__ e0, const float* __restrict__ p0,
    const float* __restrict__ e1, const float* __restrict__ p1,
    const float* __restrict__ e2, const float* __restrict__ p2,
    const float* __restrict__ e3, const float* __restrict__ p3,
    const int* __restrict__ counts, const int* __restrict__ lists,
    float* __restrict__ out, int n) {
  extern __shared__ char smem[];
  switch (blockIdx.z) {
    case 0: gemm_body<0, 1024,      0>(inp, e0, p0, counts, lists, out, n, smem); break;
    case 1: gemm_body<1,  256,  20000>(inp, e1, p1, counts, lists, out, n, smem); break;
    case 2: gemm_body<2,   64,  40000>(inp, e2, p2, counts, lists, out, n, smem); break;
    case 3: gemm_body<3,   16, 200000>(inp, e3, p3, counts, lists, out, n, smem); break;
  }
}

// ---------------------------------------------------------------------------
// Input order (setup_inputs dict order!): inp, emb0, proj0, emb1, proj1,
// emb2, proj2, emb3, proj3.
// ---------------------------------------------------------------------------
extern "C" void kernel_launch(void* const* d_in, const int* in_sizes, int n_in,
                              void* d_out, int out_size, void* d_ws, size_t ws_size,
                              hipStream_t stream) {
  const int*   inp   = (const int*)d_in[0];
  const float* emb0  = (const float*)d_in[1];
  const float* proj0 = (const float*)d_in[2];
  const float* emb1  = (const float*)d_in[3];
  const float* proj1 = (const float*)d_in[4];
  const float* emb2  = (const float*)d_in[5];
  const float* proj2 = (const float*)d_in[6];
  const float* emb3  = (const float*)d_in[7];
  const float* proj3 = (const float*)d_in[8];
  float* out = (float*)d_out;
  const int n = in_sizes[0];  // 16384 tokens

  int* counts = (int*)d_ws;        // 4 ints
  int* lists  = (int*)d_ws + 4;    // 4 x n ints

  hipMemsetAsync(counts, 0, 4 * sizeof(int), stream);
  classify_kernel<<<dim3((n + 255) / 256), dim3(256), 0, stream>>>(inp, n, counts, lists);

  dim3 grid(DPROJ / 128, (n + 63) / 64, 4);  // 8 x 256 x 4; empty tiles early-exit
  size_t smem_bytes = (size_t)(64 + 128) * 68 * 4 + 2 * 64 * 4;  // 52736 B (max variant)
  gemm_all<<<grid, dim3(256), smem_bytes, stream>>>(inp, emb0, proj0, emb1, proj1,
                                                    emb2, proj2, emb3, proj3,
                                                    counts, lists, out, n);
}

// Round 2
// 54.953 us; speedup vs baseline: 4.6814x; 4.6814x over previous
//
#include <hip/hip_runtime.h>

#define DPROJ 1024

typedef short  bf16x8  __attribute__((ext_vector_type(8)));
typedef float  f32x4   __attribute__((ext_vector_type(4)));
typedef unsigned short u16x4 __attribute__((ext_vector_type(4)));

__device__ __forceinline__ unsigned short f2bf(float f) {
  unsigned u = __builtin_bit_cast(unsigned, f);
  u += 0x7FFFu + ((u >> 16) & 1u);          // round-to-nearest-even
  return (unsigned short)(u >> 16);
}

// ---------------------------------------------------------------------------
// Kernel 1: classify tokens into 4 bucket lists. Wave-aggregated atomics:
// one atomicAdd per (wave, bucket) instead of per token. List order is
// nondeterministic but each token's output value is position-independent.
// ---------------------------------------------------------------------------
__global__ __launch_bounds__(256) void classify_kernel(const int* __restrict__ inp, int n,
                                                       int* __restrict__ counts,
                                                       int* __restrict__ lists) {
  int t = blockIdx.x * 256 + threadIdx.x;
  int lane = threadIdx.x & 63;
  int v = (t < n) ? inp[t] : -1;
  int b = (v < 0) ? -1 : (v >= 200000) ? 3 : (v >= 40000) ? 2 : (v >= 20000) ? 1 : 0;
#pragma unroll
  for (int i = 0; i < 4; ++i) {
    unsigned long long m = __ballot(b == i);
    if (b == i) {
      int rank = __popcll(m & ((1ull << lane) - 1ull));
      int src  = __ffsll((unsigned long long)m) - 1;
      int base = 0;
      if (lane == src) base = atomicAdd(&counts[i], __popcll(m));
      base = __shfl(base, src);
      lists[i * n + base + rank] = t;
    }
  }
}

// ---------------------------------------------------------------------------
// Kernel 2: per-bucket GEMM on bf16 MFMA (16x16x32, fp32 accum).
// Block = 256 thr (4 waves, 2x2), tile = 64 tokens x 128 cols, K-chunk = 64.
// LDS tiles bf16 with XOR swizzle byte ^= (row&7)<<4 (128B rows -> else
// 16-way bank conflict on ds_read_b128, per G4).
// ---------------------------------------------------------------------------
template <int B, int D, int L>
__device__ __forceinline__ void gemm_body(const int* __restrict__ inp,
                                          const float* __restrict__ emb,
                                          const float* __restrict__ proj,
                                          const int* __restrict__ counts,
                                          const int* __restrict__ lists,
                                          float* __restrict__ out,
                                          int n, char* smem) {
  constexpr int CH = (D + 63) / 64;        // K-chunks: 16,4,1,1
  constexpr int KR = (D < 64) ? D : 64;    // real k per chunk (D=16 -> 16, zero-pad rest)
  const int cnt = counts[B];
  const int r0  = blockIdx.y * 64;
  if (r0 >= cnt) return;
  const int c0   = blockIdx.x * 128;
  const int tid  = threadIdx.x;
  const int lane = tid & 63;
  const int w    = tid >> 6;               // wave 0..3
  const int wr   = w >> 1, wc = w & 1;     // 2x2 wave grid
  const int lr   = lane & 15, t16 = lane >> 4;

  char* Ab  = smem;                        // A tile: 64 rows x 128 B (bf16)  = 8 KB
  char* Bb  = smem + 8192;                 // B tile: 128 rows x 128 B (bf16) = 16 KB
  int* toks = (int*)(smem + 8192 + 16384);
  int* rows = toks + 64;

  if (tid < 64) {
    int p  = r0 + tid;
    int tk = (p < cnt) ? lists[B * n + p] : -1;
    toks[tid] = tk;
    rows[tid] = (tk >= 0) ? (inp[tk] - L) : 0;   // pad rows -> row 0 (stores suppressed)
  }
  __syncthreads();

  f32x4 acc[2][4];
#pragma unroll
  for (int fi = 0; fi < 2; ++fi)
#pragma unroll
    for (int fj = 0; fj < 4; ++fj) acc[fi][fj] = (f32x4){0.f, 0.f, 0.f, 0.f};

  for (int ch = 0; ch < CH; ++ch) {
    const int k0 = ch * 64;
    // ---- stage A: 64 x 64 (1024 float4-quads), convert fp32->bf16, swizzled write
#pragma unroll
    for (int i = 0; i < 4; ++i) {
      int q = tid + i * 256;
      int r = q >> 4, c4 = (q & 15) * 4;
      float4 v = make_float4(0.f, 0.f, 0.f, 0.f);
      if (KR == 64 || c4 < KR)
        v = *reinterpret_cast<const float4*>(emb + (size_t)rows[r] * D + k0 + c4);
      u16x4 o = {f2bf(v.x), f2bf(v.y), f2bf(v.z), f2bf(v.w)};
      *reinterpret_cast<u16x4*>(Ab + r * 128 + ((c4 * 2) ^ ((r & 7) << 4))) = o;
    }
    // ---- stage B: 128 x 64 (2048 quads)
#pragma unroll
    for (int i = 0; i < 8; ++i) {
      int q = tid + i * 256;
      int c = q >> 4, c4 = (q & 15) * 4;
      float4 v = make_float4(0.f, 0.f, 0.f, 0.f);
      if (KR == 64 || c4 < KR)
        v = *reinterpret_cast<const float4*>(proj + (size_t)(c0 + c) * D + k0 + c4);
      u16x4 o = {f2bf(v.x), f2bf(v.y), f2bf(v.z), f2bf(v.w)};
      *reinterpret_cast<u16x4*>(Bb + c * 128 + ((c4 * 2) ^ ((c & 7) << 4))) = o;
    }
    __syncthreads();

#pragma unroll
    for (int s = 0; s < 2; ++s) {          // two K=32 MFMA steps per chunk
      bf16x8 a[2], b[4];
#pragma unroll
      for (int fi = 0; fi < 2; ++fi) {
        int row = wr * 32 + fi * 16 + lr;
        a[fi] = *reinterpret_cast<const bf16x8*>(
            Ab + row * 128 + ((s * 64 + t16 * 16) ^ ((row & 7) << 4)));
      }
#pragma unroll
      for (int fj = 0; fj < 4; ++fj) {
        int col = wc * 64 + fj * 16 + lr;
        b[fj] = *reinterpret_cast<const bf16x8*>(
            Bb + col * 128 + ((s * 64 + t16 * 16) ^ ((col & 7) << 4)));
      }
#pragma unroll
      for (int fi = 0; fi < 2; ++fi)
#pragma unroll
        for (int fj = 0; fj < 4; ++fj)
          acc[fi][fj] = __builtin_amdgcn_mfma_f32_16x16x32_bf16(a[fi], b[fj], acc[fi][fj], 0, 0, 0);
    }
    __syncthreads();
  }

  // ---- epilogue: C/D layout col = lane&15, row = (lane>>4)*4 + reg (HW-verified)
#pragma unroll
  for (int fi = 0; fi < 2; ++fi) {
    int rbase = wr * 32 + fi * 16 + t16 * 4;
#pragma unroll
    for (int reg = 0; reg < 4; ++reg) {
      int p = rbase + reg;
      if (r0 + p < cnt) {
        int tk = toks[p];
        float* o = out + (size_t)tk * DPROJ + c0 + wc * 64 + lr;
#pragma unroll
        for (int fj = 0; fj < 4; ++fj) o[fj * 16] = acc[fi][fj][reg];
      }
    }
  }
}

__global__ __launch_bounds__(256) void gemm_all(
    const int* __restrict__ inp,
    const float* __restrict__ e0, const float* __restrict__ p0,
    const float* __restrict__ e1, const float* __restrict__ p1,
    const float* __restrict__ e2, const float* __restrict__ p2,
    const float* __restrict__ e3, const float* __restrict__ p3,
    const int* __restrict__ counts, const int* __restrict__ lists,
    float* __restrict__ out, int n) {
  extern __shared__ char smem[];
  switch (blockIdx.z) {
    case 0: gemm_body<0, 1024,      0>(inp, e0, p0, counts, lists, out, n, smem); break;
    case 1: gemm_body<1,  256,  20000>(inp, e1, p1, counts, lists, out, n, smem); break;
    case 2: gemm_body<2,   64,  40000>(inp, e2, p2, counts, lists, out, n, smem); break;
    case 3: gemm_body<3,   16, 200000>(inp, e3, p3, counts, lists, out, n, smem); break;
  }
}

// ---------------------------------------------------------------------------
// Input order (setup_inputs dict order): inp, emb0..emb3 interleaved? NO --
// dict order is inp, emb0, emb1, emb2, emb3 built in the first loop? Check:
// setup builds out["emb{i}"] for i in 0..3 THEN out["proj{i}"] in same loop
// iteration -- emb and proj alternate: emb0, proj0? No: the loop body sets
// emb{i} then proj{i} uses ks[5+i] but assignment order within one loop
// iteration is emb{i}, proj{i}. So order: inp, emb0, proj0, emb1, proj1, ...
// ---------------------------------------------------------------------------
extern "C" void kernel_launch(void* const* d_in, const int* in_sizes, int n_in,
                              void* d_out, int out_size, void* d_ws, size_t ws_size,
                              hipStream_t stream) {
  const int*   inp   = (const int*)d_in[0];
  const float* emb0  = (const float*)d_in[1];
  const float* proj0 = (const float*)d_in[2];
  const float* emb1  = (const float*)d_in[3];
  const float* proj1 = (const float*)d_in[4];
  const float* emb2  = (const float*)d_in[5];
  const float* proj2 = (const float*)d_in[6];
  const float* emb3  = (const float*)d_in[7];
  const float* proj3 = (const float*)d_in[8];
  float* out = (float*)d_out;
  const int n = in_sizes[0];  // 16384 tokens

  int* counts = (int*)d_ws;      // 4 ints
  int* lists  = (int*)d_ws + 4;  // 4 x n ints

  hipMemsetAsync(counts, 0, 4 * sizeof(int), stream);
  classify_kernel<<<dim3((n + 255) / 256), dim3(256), 0, stream>>>(inp, n, counts, lists);

  dim3 grid(DPROJ / 128, (n + 63) / 64, 4);   // 8 x 256 x 4; empty tiles early-exit
  size_t smem_bytes = 8192 + 16384 + 2 * 64 * sizeof(int);  // 25088 B
  gemm_all<<<grid, dim3(256), smem_bytes, stream>>>(inp, emb0, proj0, emb1, proj1,
                                                    emb2, proj2, emb3, proj3,
                                                    counts, lists, out, n);
}